// Round 2
// baseline (58991.003 us; speedup 1.0000x reference)
//
#include <hip/hip_runtime.h>
#include <hip/hip_bf16.h>
#include <math.h>

// ---------------------------------------------------------------------------
// SuperPoint point head, f64-accumulation version (NMS exact-equality needs
// score ordering to match the float64 numpy reference; fp32 flips ~tens of
// windows -> absmax ~0.02).  Convs run per-batch to halve the f64 footprint.
// ---------------------------------------------------------------------------

#define B_      16
#define HC      60
#define WC      80
#define PIX     (HC * WC)          // 4800
#define HF      480
#define WF      640
#define IMG     (HF * WF)          // 307200
#define NPIX    (B_ * IMG)         // 4915200

__device__ __forceinline__ int clampi(int v, int lo, int hi) {
    return v < lo ? lo : (v > hi ? hi : v);
}

// ---------------------------------------------------------------------------
__global__ __launch_bounds__(256) void cvt_f32_f64(const float* __restrict__ s,
                                                   double* __restrict__ d, int n)
{
    int i = blockIdx.x * 256 + threadIdx.x;
    if (i < n) d[i] = (double)s[i];
}

// ---------------------------------------------------------------------------
// conv 3x3, pad 1, + bias (+ optional ReLU), f64 accumulate. Single batch.
// block: 256 threads -> 240 active = 3 rows x 80 cols. grid: (20, COUT/16)
// Weights are f64, block-uniform address -> compiler emits s_load (SGPR
// operand feeds v_fma_f64 directly).
// ---------------------------------------------------------------------------
template <int CIN, typename TIN, bool RELU>
__global__ __launch_bounds__(256) void conv3x3_f64(
    const TIN* __restrict__ in,      // [CIN][60][80]
    const double* __restrict__ w,    // [COUT][CIN][3][3]
    const double* __restrict__ bias, // [COUT]
    double* __restrict__ out,        // [COUT][60][80]
    int COUT)
{
    const int ytile = blockIdx.x;          // 0..19
    const int oc0   = blockIdx.y * 16;
    const int tid   = threadIdx.x;
    const int r     = tid / WC;            // 0..2 active, 3 idle
    const int cx    = tid % WC;
    const int y0    = ytile * 3;

    __shared__ double sin_[5][84];         // rows y0-1..y0+3, cols -1..80

    double acc[16];
#pragma unroll
    for (int o = 0; o < 16; ++o) acc[o] = 0.0;

    for (int ic = 0; ic < CIN; ++ic) {
        __syncthreads();
        for (int i = tid; i < 5 * 82; i += 256) {
            int ry = i / 82, rx = i % 82;
            int gy = y0 - 1 + ry, gx = rx - 1;
            double v = 0.0;
            if ((unsigned)gy < (unsigned)HC && (unsigned)gx < (unsigned)WC)
                v = (double)in[(size_t)ic * PIX + gy * WC + gx];
            sin_[ry][rx] = v;
        }
        __syncthreads();

        if (r < 3) {
            double v00 = sin_[r + 0][cx + 0], v01 = sin_[r + 0][cx + 1], v02 = sin_[r + 0][cx + 2];
            double v10 = sin_[r + 1][cx + 0], v11 = sin_[r + 1][cx + 1], v12 = sin_[r + 1][cx + 2];
            double v20 = sin_[r + 2][cx + 0], v21 = sin_[r + 2][cx + 1], v22 = sin_[r + 2][cx + 2];
            const double* wp = w + ((size_t)oc0 * CIN + ic) * 9;
#pragma unroll
            for (int o = 0; o < 16; ++o) {
                const double* wo = wp + (size_t)o * CIN * 9;
                acc[o] += v00 * wo[0] + v01 * wo[1] + v02 * wo[2]
                        + v10 * wo[3] + v11 * wo[4] + v12 * wo[5]
                        + v20 * wo[6] + v21 * wo[7] + v22 * wo[8];
            }
        }
    }

    if (r < 3) {
        int y = y0 + r;
        double* ob = out + (size_t)y * WC + cx;
#pragma unroll
        for (int o = 0; o < 16; ++o) {
            double v = acc[o] + bias[oc0 + o];
            if (RELU) v = fmax(v, 0.0);
            ob[(size_t)(oc0 + o) * PIX] = v;
        }
    }
}

// ---------------------------------------------------------------------------
// conv1x1 (128->65) + softmax(65)[:64] + pixel-unshuffle.  Single batch.
// ---------------------------------------------------------------------------
__global__ __launch_bounds__(256) void conv1x1_softmax_f64(
    const double* __restrict__ h2,   // [128][4800]
    const double* __restrict__ wg,   // [65][128]
    const double* __restrict__ bg,   // [65]
    double* __restrict__ S)          // [480][640] (this batch)
{
    int p = blockIdx.x * 256 + threadIdx.x;
    if (p >= PIX) return;
    const double* h2p = h2 + p;

    double l[65];
#pragma unroll
    for (int o = 0; o < 65; ++o) l[o] = bg[o];

    for (int icc = 0; icc < 128; icc += 8) {
        double h[8];
#pragma unroll
        for (int k = 0; k < 8; ++k) h[k] = h2p[(size_t)(icc + k) * PIX];
#pragma unroll
        for (int o = 0; o < 65; ++o) {
            const double* wp = wg + o * 128 + icc;
            l[o] += h[0] * wp[0] + h[1] * wp[1] + h[2] * wp[2] + h[3] * wp[3]
                  + h[4] * wp[4] + h[5] * wp[5] + h[6] * wp[6] + h[7] * wp[7];
        }
    }

    double m = l[0];
#pragma unroll
    for (int o = 1; o < 65; ++o) m = fmax(m, l[o]);
    double s = 0.0;
#pragma unroll
    for (int o = 0; o < 65; ++o) { l[o] = exp(l[o] - m); s += l[o]; }
    double inv = 1.0 / s;

    int y = p / WC, x = p % WC;
#pragma unroll
    for (int cy = 0; cy < 8; ++cy)
#pragma unroll
        for (int cx2 = 0; cx2 < 8; ++cx2)
            S[(y * 8 + cy) * WF + x * 8 + cx2] = l[cy * 8 + cx2] * inv;
}

// ---------------------------------------------------------------------------
// NMS passes on f64 scores (equality decisions must be f64-exact).
// ---------------------------------------------------------------------------
__global__ __launch_bounds__(256) void hmax9_f64(const double* __restrict__ in,
                                                 double* __restrict__ out)
{
    int p = blockIdx.x * 256 + threadIdx.x;
    int x = p % WF;
    const double* row = in + (p - x);
    double m = row[x];
#pragma unroll
    for (int d = 1; d <= 4; ++d) {
        m = fmax(m, row[clampi(x - d, 0, WF - 1)]);
        m = fmax(m, row[clampi(x + d, 0, WF - 1)]);
    }
    out[p] = m;
}

__global__ __launch_bounds__(256) void vmax9_eq(const double* __restrict__ T,
                                                const double* __restrict__ S,
                                                unsigned char* __restrict__ M)
{
    int p = blockIdx.x * 256 + threadIdx.x;
    int y = (p % IMG) / WF;
    double m = T[p];
#pragma unroll
    for (int d = 1; d <= 4; ++d) {
        m = fmax(m, T[p + (clampi(y - d, 0, HF - 1) - y) * WF]);
        m = fmax(m, T[p + (clampi(y + d, 0, HF - 1) - y) * WF]);
    }
    M[p] = (S[p] == m) ? (unsigned char)1 : (unsigned char)0;
}

__global__ __launch_bounds__(256) void hor9_u8(const unsigned char* __restrict__ in,
                                               unsigned char* __restrict__ out)
{
    int p = blockIdx.x * 256 + threadIdx.x;
    int x = p % WF;
    const unsigned char* row = in + (p - x);
    unsigned char m = row[x];
#pragma unroll
    for (int d = 1; d <= 4; ++d) {
        m = m | row[clampi(x - d, 0, WF - 1)];
        m = m | row[clampi(x + d, 0, WF - 1)];
    }
    out[p] = m;
}

__global__ __launch_bounds__(256) void vor9_sup(const unsigned char* __restrict__ T8,
                                                unsigned char* __restrict__ SUP)
{
    int p = blockIdx.x * 256 + threadIdx.x;
    int y = (p % IMG) / WF;
    unsigned char m = T8[p];
#pragma unroll
    for (int d = 1; d <= 4; ++d) {
        m = m | T8[p + (clampi(y - d, 0, HF - 1) - y) * WF];
        m = m | T8[p + (clampi(y + d, 0, HF - 1) - y) * WF];
    }
    SUP[p] = m;
}

// horizontal max of (SUP ? 0 : S)
__global__ __launch_bounds__(256) void hmax9_supp(const double* __restrict__ S,
                                                  const unsigned char* __restrict__ SUP,
                                                  double* __restrict__ T)
{
    int p = blockIdx.x * 256 + threadIdx.x;
    int x = p % WF;
    int base = p - x;
    double m = SUP[p] ? 0.0 : S[p];
#pragma unroll
    for (int d = 1; d <= 4; ++d) {
        int i1 = base + clampi(x - d, 0, WF - 1);
        int i2 = base + clampi(x + d, 0, WF - 1);
        m = fmax(m, SUP[i1] ? 0.0 : S[i1]);
        m = fmax(m, SUP[i2] ? 0.0 : S[i2]);
    }
    T[p] = m;
}

__global__ __launch_bounds__(256) void vmax9_newmask(const double* __restrict__ T,
                                                     const double* __restrict__ S,
                                                     const unsigned char* __restrict__ SUP,
                                                     unsigned char* __restrict__ M)
{
    int p = blockIdx.x * 256 + threadIdx.x;
    int y = (p % IMG) / WF;
    double m = T[p];
#pragma unroll
    for (int d = 1; d <= 4; ++d) {
        m = fmax(m, T[p + (clampi(y - d, 0, HF - 1) - y) * WF]);
        m = fmax(m, T[p + (clampi(y + d, 0, HF - 1) - y) * WF]);
    }
    unsigned char nw = (!SUP[p] && S[p] == m) ? 1 : 0;
    M[p] = M[p] | nw;
}

__global__ __launch_bounds__(256) void final_mask(const double* __restrict__ S,
                                                  const unsigned char* __restrict__ M,
                                                  float* __restrict__ out)
{
    int p = blockIdx.x * 256 + threadIdx.x;
    out[p] = M[p] ? (float)S[p] : 0.f;
}

// ---------------------------------------------------------------------------
extern "C" void kernel_launch(void* const* d_in, const int* in_sizes, int n_in,
                              void* d_out, int out_size, void* d_ws, size_t ws_size,
                              hipStream_t stream)
{
    const float* x   = (const float*)d_in[0];
    const float* wPa = (const float*)d_in[1];
    const float* bPa = (const float*)d_in[2];
    const float* wPd = (const float*)d_in[3];
    const float* bPd = (const float*)d_in[4];
    const float* wPg = (const float*)d_in[5];
    const float* bPg = (const float*)d_in[6];
    float* out = (float*)d_out;

    char* ws = (char*)d_ws;
    // persistent (NMS phase):
    double*        S   = (double*)(ws);                        // 39,321,600 B
    double*        T   = (double*)(ws + 39321600);             // 39,321,600 B
    unsigned char* M   = (unsigned char*)(ws + 78643200);      //  4,915,200 B
    unsigned char* SUP = (unsigned char*)(ws + 83558400);      //  4,915,200 B
    unsigned char* T8  = (unsigned char*)(ws + 88473600);      //  4,915,200 B
    // conv-phase overlay (inside T region, dead until NMS starts):
    double* w1d = (double*)(ws + 39321600);   // 256*512*9*8 = 9,437,184
    double* w2d = (double*)(ws + 48758784);   // 128*256*9*8 = 2,359,296
    double* wgd = (double*)(ws + 51118080);   // 65*128*8    =    66,560
    double* b1d = (double*)(ws + 51184640);   // 2,048
    double* b2d = (double*)(ws + 51186688);   // 1,024
    double* bgd = (double*)(ws + 51187712);   // 520 (pad to 1,024)
    double* h1s = (double*)(ws + 51188736);   // 256*4800*8  = 9,830,400
    double* h2s = (double*)(ws + 61019136);   // 128*4800*8  = 4,915,200
    // ends at 65,934,336 < 78,643,200 (fits in T region)

    // weights -> f64 (recomputed every call; deterministic)
    cvt_f32_f64<<<(1179648 + 255) / 256, 256, 0, stream>>>(wPa, w1d, 1179648);
    cvt_f32_f64<<<(294912 + 255) / 256, 256, 0, stream>>>(wPd, w2d, 294912);
    cvt_f32_f64<<<(8320 + 255) / 256, 256, 0, stream>>>(wPg, wgd, 8320);
    cvt_f32_f64<<<1, 256, 0, stream>>>(bPa, b1d, 256);
    cvt_f32_f64<<<1, 256, 0, stream>>>(bPd, b2d, 128);
    cvt_f32_f64<<<1, 256, 0, stream>>>(bPg, bgd, 65);

    for (int b = 0; b < B_; ++b) {
        const float* xb = x + (size_t)b * 512 * PIX;
        conv3x3_f64<512, float, true><<<dim3(20, 16), 256, 0, stream>>>(xb, w1d, b1d, h1s, 256);
        conv3x3_f64<256, double, true><<<dim3(20, 8), 256, 0, stream>>>(h1s, w2d, b2d, h2s, 128);
        conv1x1_softmax_f64<<<19, 256, 0, stream>>>(h2s, wgd, bgd, S + (size_t)b * IMG);
    }

    const int NB = NPIX / 256;  // 19200
    hmax9_f64<<<NB, 256, 0, stream>>>(S, T);
    vmax9_eq<<<NB, 256, 0, stream>>>(T, S, M);
    for (int it = 0; it < 2; ++it) {
        hor9_u8<<<NB, 256, 0, stream>>>(M, T8);
        vor9_sup<<<NB, 256, 0, stream>>>(T8, SUP);
        hmax9_supp<<<NB, 256, 0, stream>>>(S, SUP, T);
        vmax9_newmask<<<NB, 256, 0, stream>>>(T, S, SUP, M);
    }
    final_mask<<<NB, 256, 0, stream>>>(S, M, out);
}

// Round 3
// 8136.109 us; speedup vs baseline: 7.2505x; 7.2505x over previous
//
#include <hip/hip_runtime.h>
#include <hip/hip_bf16.h>
#include <math.h>

// ---------------------------------------------------------------------------
// SuperPoint point head, f64 end-to-end (NMS exact-equality requires score
// ordering identical to the float64 numpy reference; fp32 flips windows).
// Round 3: batch dimension moved into the grid (fixes 13% occupancy / 9%
// VALUBusy latency-bound profile of round 2), 4-ic LDS staging chunks,
// runtime batch-group sizing G from ws_size.
// ---------------------------------------------------------------------------

#define B_      16
#define HC      60
#define WC      80
#define PIX     (HC * WC)          // 4800
#define HF      480
#define WF      640
#define IMG     (HF * WF)          // 307200
#define NPIX    (B_ * IMG)         // 4915200

__device__ __forceinline__ int clampi(int v, int lo, int hi) {
    return v < lo ? lo : (v > hi ? hi : v);
}

// ---------------------------------------------------------------------------
__global__ __launch_bounds__(256) void cvt_f32_f64(const float* __restrict__ s,
                                                   double* __restrict__ d, int n)
{
    int i = blockIdx.x * 256 + threadIdx.x;
    if (i < n) d[i] = (double)s[i];
}

// ---------------------------------------------------------------------------
// conv 3x3, pad 1, + bias (+ optional ReLU), f64 accumulate.
// block: 256 threads -> 240 active = 3 rows x 80 cols.
// grid: (20 ytiles, COUT/16, G batches).  4 input channels staged per barrier.
// Weights are f64 at block-uniform addresses -> s_load chains, hidden by
// ~8 resident blocks/CU.
// ---------------------------------------------------------------------------
template <int CIN, typename TIN, bool RELU>
__global__ __launch_bounds__(256) void conv3x3_f64(
    const TIN* __restrict__ in,      // [G][CIN][60][80]
    const double* __restrict__ w,    // [COUT][CIN][3][3]
    const double* __restrict__ bias, // [COUT]
    double* __restrict__ out,        // [G][COUT][60][80]
    int COUT)
{
    const int ytile = blockIdx.x;          // 0..19
    const int oc0   = blockIdx.y * 16;
    const int b     = blockIdx.z;
    const int tid   = threadIdx.x;
    const int r     = tid / WC;            // 0..2 active, 3 idle for compute
    const int cx    = tid % WC;
    const int y0    = ytile * 3;

    in  += (size_t)b * CIN  * PIX;
    out += (size_t)b * COUT * PIX;

    __shared__ double sin_[4][5][82];      // 4 ic x rows y0-1..y0+3 x cols -1..80

    double acc[16];
#pragma unroll
    for (int o = 0; o < 16; ++o) acc[o] = 0.0;

    for (int icc = 0; icc < CIN; icc += 4) {
        __syncthreads();
        for (int i = tid; i < 4 * 5 * 82; i += 256) {
            int ick = i / 410;
            int rem = i - ick * 410;
            int ry  = rem / 82, rx = rem - ry * 82;
            int gy  = y0 - 1 + ry, gx = rx - 1;
            double v = 0.0;
            if ((unsigned)gy < (unsigned)HC && (unsigned)gx < (unsigned)WC)
                v = (double)in[(size_t)(icc + ick) * PIX + gy * WC + gx];
            sin_[ick][ry][rx] = v;
        }
        __syncthreads();

        if (r < 3) {
            for (int k = 0; k < 4; ++k) {
                const int ic = icc + k;
                double v00 = sin_[k][r + 0][cx + 0], v01 = sin_[k][r + 0][cx + 1], v02 = sin_[k][r + 0][cx + 2];
                double v10 = sin_[k][r + 1][cx + 0], v11 = sin_[k][r + 1][cx + 1], v12 = sin_[k][r + 1][cx + 2];
                double v20 = sin_[k][r + 2][cx + 0], v21 = sin_[k][r + 2][cx + 1], v22 = sin_[k][r + 2][cx + 2];
                const double* wp = w + ((size_t)oc0 * CIN + ic) * 9;
#pragma unroll
                for (int o = 0; o < 16; ++o) {
                    const double* wo = wp + (size_t)o * CIN * 9;
                    acc[o] += v00 * wo[0] + v01 * wo[1] + v02 * wo[2]
                            + v10 * wo[3] + v11 * wo[4] + v12 * wo[5]
                            + v20 * wo[6] + v21 * wo[7] + v22 * wo[8];
                }
            }
        }
    }

    if (r < 3) {
        int y = y0 + r;
        double* ob = out + (size_t)y * WC + cx;
#pragma unroll
        for (int o = 0; o < 16; ++o) {
            double v = acc[o] + bias[oc0 + o];
            if (RELU) v = fmax(v, 0.0);
            ob[(size_t)(oc0 + o) * PIX] = v;
        }
    }
}

// ---------------------------------------------------------------------------
// conv1x1 (128->65) + softmax(65)[:64] + pixel-unshuffle.  grid (19, G).
// ---------------------------------------------------------------------------
__global__ __launch_bounds__(256) void conv1x1_softmax_f64(
    const double* __restrict__ h2,   // [G][128][4800]
    const double* __restrict__ wg,   // [65][128]
    const double* __restrict__ bg,   // [65]
    double* __restrict__ S)          // [G][480][640]
{
    int p = blockIdx.x * 256 + threadIdx.x;
    if (p >= PIX) return;
    const int b = blockIdx.y;
    const double* h2p = h2 + (size_t)b * 128 * PIX + p;
    double* Sb = S + (size_t)b * IMG;

    double l[65];
#pragma unroll
    for (int o = 0; o < 65; ++o) l[o] = bg[o];

    for (int icc = 0; icc < 128; icc += 8) {
        double h[8];
#pragma unroll
        for (int k = 0; k < 8; ++k) h[k] = h2p[(size_t)(icc + k) * PIX];
#pragma unroll
        for (int o = 0; o < 65; ++o) {
            const double* wp = wg + o * 128 + icc;
            l[o] += h[0] * wp[0] + h[1] * wp[1] + h[2] * wp[2] + h[3] * wp[3]
                  + h[4] * wp[4] + h[5] * wp[5] + h[6] * wp[6] + h[7] * wp[7];
        }
    }

    double m = l[0];
#pragma unroll
    for (int o = 1; o < 65; ++o) m = fmax(m, l[o]);
    double s = 0.0;
#pragma unroll
    for (int o = 0; o < 65; ++o) { l[o] = exp(l[o] - m); s += l[o]; }
    double inv = 1.0 / s;

    int y = p / WC, x = p % WC;
#pragma unroll
    for (int cy = 0; cy < 8; ++cy)
#pragma unroll
        for (int cx2 = 0; cx2 < 8; ++cx2)
            Sb[(y * 8 + cy) * WF + x * 8 + cx2] = l[cy * 8 + cx2] * inv;
}

// ---------------------------------------------------------------------------
// NMS passes on f64 scores (equality decisions must be f64-exact).
// ---------------------------------------------------------------------------
__global__ __launch_bounds__(256) void hmax9_f64(const double* __restrict__ in,
                                                 double* __restrict__ out)
{
    int p = blockIdx.x * 256 + threadIdx.x;
    int x = p % WF;
    const double* row = in + (p - x);
    double m = row[x];
#pragma unroll
    for (int d = 1; d <= 4; ++d) {
        m = fmax(m, row[clampi(x - d, 0, WF - 1)]);
        m = fmax(m, row[clampi(x + d, 0, WF - 1)]);
    }
    out[p] = m;
}

__global__ __launch_bounds__(256) void vmax9_eq(const double* __restrict__ T,
                                                const double* __restrict__ S,
                                                unsigned char* __restrict__ M)
{
    int p = blockIdx.x * 256 + threadIdx.x;
    int y = (p % IMG) / WF;
    double m = T[p];
#pragma unroll
    for (int d = 1; d <= 4; ++d) {
        m = fmax(m, T[p + (clampi(y - d, 0, HF - 1) - y) * WF]);
        m = fmax(m, T[p + (clampi(y + d, 0, HF - 1) - y) * WF]);
    }
    M[p] = (S[p] == m) ? (unsigned char)1 : (unsigned char)0;
}

__global__ __launch_bounds__(256) void hor9_u8(const unsigned char* __restrict__ in,
                                               unsigned char* __restrict__ out)
{
    int p = blockIdx.x * 256 + threadIdx.x;
    int x = p % WF;
    const unsigned char* row = in + (p - x);
    unsigned char m = row[x];
#pragma unroll
    for (int d = 1; d <= 4; ++d) {
        m = m | row[clampi(x - d, 0, WF - 1)];
        m = m | row[clampi(x + d, 0, WF - 1)];
    }
    out[p] = m;
}

__global__ __launch_bounds__(256) void vor9_sup(const unsigned char* __restrict__ T8,
                                                unsigned char* __restrict__ SUP)
{
    int p = blockIdx.x * 256 + threadIdx.x;
    int y = (p % IMG) / WF;
    unsigned char m = T8[p];
#pragma unroll
    for (int d = 1; d <= 4; ++d) {
        m = m | T8[p + (clampi(y - d, 0, HF - 1) - y) * WF];
        m = m | T8[p + (clampi(y + d, 0, HF - 1) - y) * WF];
    }
    SUP[p] = m;
}

// horizontal max of (SUP ? 0 : S)
__global__ __launch_bounds__(256) void hmax9_supp(const double* __restrict__ S,
                                                  const unsigned char* __restrict__ SUP,
                                                  double* __restrict__ T)
{
    int p = blockIdx.x * 256 + threadIdx.x;
    int x = p % WF;
    int base = p - x;
    double m = SUP[p] ? 0.0 : S[p];
#pragma unroll
    for (int d = 1; d <= 4; ++d) {
        int i1 = base + clampi(x - d, 0, WF - 1);
        int i2 = base + clampi(x + d, 0, WF - 1);
        m = fmax(m, SUP[i1] ? 0.0 : S[i1]);
        m = fmax(m, SUP[i2] ? 0.0 : S[i2]);
    }
    T[p] = m;
}

__global__ __launch_bounds__(256) void vmax9_newmask(const double* __restrict__ T,
                                                     const double* __restrict__ S,
                                                     const unsigned char* __restrict__ SUP,
                                                     unsigned char* __restrict__ M)
{
    int p = blockIdx.x * 256 + threadIdx.x;
    int y = (p % IMG) / WF;
    double m = T[p];
#pragma unroll
    for (int d = 1; d <= 4; ++d) {
        m = fmax(m, T[p + (clampi(y - d, 0, HF - 1) - y) * WF]);
        m = fmax(m, T[p + (clampi(y + d, 0, HF - 1) - y) * WF]);
    }
    unsigned char nw = (!SUP[p] && S[p] == m) ? 1 : 0;
    M[p] = M[p] | nw;
}

__global__ __launch_bounds__(256) void final_mask(const double* __restrict__ S,
                                                  const unsigned char* __restrict__ M,
                                                  float* __restrict__ out)
{
    int p = blockIdx.x * 256 + threadIdx.x;
    out[p] = M[p] ? (float)S[p] : 0.f;
}

// ---------------------------------------------------------------------------
extern "C" void kernel_launch(void* const* d_in, const int* in_sizes, int n_in,
                              void* d_out, int out_size, void* d_ws, size_t ws_size,
                              hipStream_t stream)
{
    const float* x   = (const float*)d_in[0];
    const float* wPa = (const float*)d_in[1];
    const float* bPa = (const float*)d_in[2];
    const float* wPd = (const float*)d_in[3];
    const float* bPd = (const float*)d_in[4];
    const float* wPg = (const float*)d_in[5];
    const float* bPg = (const float*)d_in[6];
    float* out = (float*)d_out;

    char* ws = (char*)d_ws;
    // ---- persistent / NMS-phase layout (93,388,800 B total; proven to fit) --
    double*        S   = (double*)(ws);                        // 39,321,600
    double*        T   = (double*)(ws + 39321600);             // 39,321,600
    unsigned char* M   = (unsigned char*)(ws + 78643200);      //  4,915,200
    unsigned char* SUP = (unsigned char*)(ws + 83558400);      //  4,915,200
    unsigned char* T8  = (unsigned char*)(ws + 88473600);      //  4,915,200
    // ---- conv-phase overlay (weights sit inside the T region, dead then) ---
    double* w1d = (double*)(ws + 39321600);   // 256*512*9*8 = 9,437,184
    double* w2d = (double*)(ws + 48758784);   // 128*256*9*8 = 2,359,296
    double* wgd = (double*)(ws + 51118080);   // 65*128*8    =    66,560
    double* b1d = (double*)(ws + 51184640);   // 2,048
    double* b2d = (double*)(ws + 51186688);   // 1,024
    double* bgd = (double*)(ws + 51187712);   // 1,024 (pad)
    char*   hbase = ws + 51188736;            // batch-group h1/h2 area

    // largest batch-group G with  51,188,736 + G*14,745,600 <= ws_size
    // (G=2 needs 80.7 MB < 93.4 MB proven minimum, so G>=2 always)
    int G = 1;
    for (int g = 16; g >= 1; g >>= 1) {
        if ((size_t)51188736 + (size_t)g * 14745600 <= ws_size) { G = g; break; }
    }

    // weights -> f64
    cvt_f32_f64<<<(1179648 + 255) / 256, 256, 0, stream>>>(wPa, w1d, 1179648);
    cvt_f32_f64<<<(294912 + 255) / 256, 256, 0, stream>>>(wPd, w2d, 294912);
    cvt_f32_f64<<<(8320 + 255) / 256, 256, 0, stream>>>(wPg, wgd, 8320);
    cvt_f32_f64<<<1, 256, 0, stream>>>(bPa, b1d, 256);
    cvt_f32_f64<<<1, 256, 0, stream>>>(bPd, b2d, 128);
    cvt_f32_f64<<<1, 256, 0, stream>>>(bPg, bgd, 65);

    for (int bg0 = 0; bg0 < B_; bg0 += G) {
        int Gc = (bg0 + G <= B_) ? G : (B_ - bg0);
        double* h1s = (double*)hbase;                                  // Gc*256*4800
        double* h2s = (double*)(hbase + (size_t)G * 9830400);          // Gc*128*4800
        const float* xb = x + (size_t)bg0 * 512 * PIX;
        conv3x3_f64<512, float, true><<<dim3(20, 16, Gc), 256, 0, stream>>>(xb, w1d, b1d, h1s, 256);
        conv3x3_f64<256, double, true><<<dim3(20, 8, Gc), 256, 0, stream>>>(h1s, w2d, b2d, h2s, 128);
        conv1x1_softmax_f64<<<dim3(19, Gc), 256, 0, stream>>>(h2s, wgd, bgd, S + (size_t)bg0 * IMG);
    }

    const int NB = NPIX / 256;  // 19200
    hmax9_f64<<<NB, 256, 0, stream>>>(S, T);
    vmax9_eq<<<NB, 256, 0, stream>>>(T, S, M);
    for (int it = 0; it < 2; ++it) {
        hor9_u8<<<NB, 256, 0, stream>>>(M, T8);
        vor9_sup<<<NB, 256, 0, stream>>>(T8, SUP);
        hmax9_supp<<<NB, 256, 0, stream>>>(S, SUP, T);
        vmax9_newmask<<<NB, 256, 0, stream>>>(T, S, SUP, M);
    }
    final_mask<<<NB, 256, 0, stream>>>(S, M, out);
}